// Round 7
// baseline (139.062 us; speedup 1.0000x reference)
//
#include <hip/hip_runtime.h>

#define A_ 16
#define NA_ 8
#define DOBS_ 64

typedef _Float16 f16;
typedef f16 h2 __attribute__((ext_vector_type(2)));
typedef f16 v8h __attribute__((ext_vector_type(8)));
typedef float v4f __attribute__((ext_vector_type(4)));

__device__ __forceinline__ float fdot2f(h2 a, h2 b, float c) {
  return __builtin_amdgcn_fdot2(a, b, c, false);
}
__device__ __forceinline__ float lrelu(float x) { return x > 0.f ? x : 0.01f * x; }

struct P {
  const float *obs, *pol, *act;
  const float *kw1w, *kw1b, *kw2w, *kw2b, *qw1w, *qw1b, *qw2w, *qw2b;
  const float *ko1w, *ko1b, *ko2w, *ko2b, *qo1w, *qo1b, *qo2w, *qo2b;
  const float *av1w, *av1b, *av2w, *av2b, *fv1w, *fv1b, *fv2w, *fv2b;
  float *out0, *out1, *out2;
};

struct alignas(16) SM {
  // persistent
  f16 obsh[16 * 72];
  float pi[128];
  float act[128];
  float wsig[256];
  float wo[256];
  float c0[16];
  f16 eh[256];
  union {
    struct {                    // FRONT
      f16 obsl[16 * 72];
      f16 Wp1[64 * 72], Wp2[64 * 72];
      f16 Wxh[64 * 72], Wxl[64 * 72];
      f16 X1h[16 * 72], X1l[16 * 72];
      f16 X2h[16 * 72], X2l[16 * 72];
      float S2[16 * 68];
      float S3G[16 * 68];
      float wz[512];
    } f;
    struct {                    // BACK (4 AO slices)
      f16 AOsrcD[16 * 72];
      f16 APT[64 * 24];
      f16 AextH[16 * 40];
      f16 fv2pw[512];
      f16 slice[4][1536];
      union { struct { f16 av1H[64 * 96]; f16 av2H[64 * 72]; } av; f16 fv1H[64 * 136]; } W;
      float av1b[64], av2b[64], fv1b[64], fv2b[8];
    } bk;
  } u;
};

__device__ __forceinline__ v4f gemm_plain(const f16* Xh, const f16* W, float bv, int nt, int lane) {
  const int m = lane & 15, q = lane >> 4;
  v4f acc = {bv, bv, bv, bv};
  const v8h a0 = *(const v8h*)(Xh + m * 72 + q * 8);
  const v8h a1 = *(const v8h*)(Xh + m * 72 + 32 + q * 8);
  const f16* wr = W + (nt * 16 + m) * 72 + q * 8;
  acc = __builtin_amdgcn_mfma_f32_16x16x32_f16(a0, *(const v8h*)wr, acc, 0, 0, 0);
  acc = __builtin_amdgcn_mfma_f32_16x16x32_f16(a1, *(const v8h*)(wr + 32), acc, 0, 0, 0);
  return acc;
}

__device__ __forceinline__ v4f gemm_tile(const f16* Xh, const f16* Xl,
                                         const f16* Wh, const f16* Wl,
                                         float bv, int nt, int lane) {
  const int m = lane & 15, q = lane >> 4;
  v4f acc = {bv, bv, bv, bv};
  const v8h ah0 = *(const v8h*)(Xh + m * 72 + q * 8);
  const v8h ah1 = *(const v8h*)(Xh + m * 72 + 32 + q * 8);
  const v8h al0 = *(const v8h*)(Xl + m * 72 + q * 8);
  const v8h al1 = *(const v8h*)(Xl + m * 72 + 32 + q * 8);
  const f16* wr = Wh + (nt * 16 + m) * 72 + q * 8;
  const v8h bh0 = *(const v8h*)(wr);
  const v8h bh1 = *(const v8h*)(wr + 32);
  const f16* wr2 = Wl + (nt * 16 + m) * 72 + q * 8;
  const v8h bl0 = *(const v8h*)(wr2);
  const v8h bl1 = *(const v8h*)(wr2 + 32);
  acc = __builtin_amdgcn_mfma_f32_16x16x32_f16(ah0, bh0, acc, 0, 0, 0);
  acc = __builtin_amdgcn_mfma_f32_16x16x32_f16(ah1, bh1, acc, 0, 0, 0);
  acc = __builtin_amdgcn_mfma_f32_16x16x32_f16(ah0, bl0, acc, 0, 0, 0);
  acc = __builtin_amdgcn_mfma_f32_16x16x32_f16(ah1, bl1, acc, 0, 0, 0);
  acc = __builtin_amdgcn_mfma_f32_16x16x32_f16(al0, bh0, acc, 0, 0, 0);
  acc = __builtin_amdgcn_mfma_f32_16x16x32_f16(al1, bh1, acc, 0, 0, 0);
  return acc;
}

__device__ __forceinline__ void writeX(f16* Xh, f16* Xl, v4f acc, int nt, int lane, bool relu) {
  const int m = lane & 15, q = lane >> 4;
#pragma unroll
  for (int reg = 0; reg < 4; reg++) {
    float y = acc[reg];
    if (relu) y = lrelu(y);
    const f16 yh = (f16)y;
    Xh[(q * 4 + reg) * 72 + nt * 16 + m] = yh;
    Xl[(q * 4 + reg) * 72 + nt * 16 + m] = (f16)(y - (float)yh);
  }
}

__device__ __forceinline__ void putP(f16* W, float4 v, int o, int rq) {
  h2* d = (h2*)(W + o * 72 + 4 * rq);
  d[0] = h2{(f16)v.x, (f16)v.y};
  d[1] = h2{(f16)v.z, (f16)v.w};
}

__device__ __forceinline__ void putW(f16* Wh, f16* Wl, float4 v, int o, int rq) {
  h2* dh = (h2*)(Wh + o * 72 + 4 * rq);
  h2* dl = (h2*)(Wl + o * 72 + 4 * rq);
  const f16 hx = (f16)v.x, hy = (f16)v.y, hz = (f16)v.z, hw = (f16)v.w;
  dh[0] = h2{hx, hy};
  dh[1] = h2{hz, hw};
  dl[0] = h2{(f16)(v.x - (float)hx), (f16)(v.y - (float)hy)};
  dl[1] = h2{(f16)(v.z - (float)hz), (f16)(v.w - (float)hw)};
}

__device__ __forceinline__ v8h bfrag(const f16* Wm, int stride, int nt, int ks, int lane) {
  const int n = lane & 15, q = lane >> 4;
  return *(const v8h*)(Wm + (nt * 16 + n) * stride + ks * 32 + q * 8);
}

__device__ __forceinline__ void av_mlp2(const f16* obsh, const f16* av1H, const f16* av2H,
                                        const float* av1b, const float* av2b,
                                        f16* Hbuf, v8h az, int lane, v4f acc2[4]) {
  const int m = lane & 15, q = lane >> 4;
  const v8h a0 = *(const v8h*)(obsh + m * 72 + q * 8);
  const v8h a1 = *(const v8h*)(obsh + m * 72 + 32 + q * 8);
#pragma unroll
  for (int nt = 0; nt < 4; nt++) {
    const float bv = av1b[nt * 16 + m];
    v4f acc = {bv, bv, bv, bv};
    acc = __builtin_amdgcn_mfma_f32_16x16x32_f16(a0, bfrag(av1H, 96, nt, 0, lane), acc, 0, 0, 0);
    acc = __builtin_amdgcn_mfma_f32_16x16x32_f16(a1, bfrag(av1H, 96, nt, 1, lane), acc, 0, 0, 0);
    acc = __builtin_amdgcn_mfma_f32_16x16x32_f16(az, bfrag(av1H, 96, nt, 2, lane), acc, 0, 0, 0);
#pragma unroll
    for (int reg = 0; reg < 4; reg++)
      Hbuf[(q * 4 + reg) * 72 + nt * 16 + m] = (f16)lrelu(acc[reg]);
  }
  const v8h h0 = *(const v8h*)(Hbuf + m * 72 + q * 8);
  const v8h h1 = *(const v8h*)(Hbuf + m * 72 + 32 + q * 8);
#pragma unroll
  for (int nt = 0; nt < 4; nt++) {
    const float bv = av2b[nt * 16 + m];
    v4f acc = {bv, bv, bv, bv};
    acc = __builtin_amdgcn_mfma_f32_16x16x32_f16(h0, bfrag(av2H, 72, nt, 0, lane), acc, 0, 0, 0);
    acc = __builtin_amdgcn_mfma_f32_16x16x32_f16(h1, bfrag(av2H, 72, nt, 1, lane), acc, 0, 0, 0);
    acc2[nt] = acc;
  }
}

// 512 threads, 4 waves/EU => 2 blocks/CU co-resident (VGPR <= 128)
__global__ __launch_bounds__(512, 4) void critic_fused(P p) {
  __shared__ SM s;
  const int tid = threadIdx.x;
  const int b = blockIdx.x >> 2, iq = blockIdx.x & 3;
  const int w = tid >> 6, lane = tid & 63;
  const int m = lane & 15, quad = lane >> 4;
  const int o = tid & 63, r8 = tid >> 6;

  // ---- t0 loads: only what P0 stages (pipelined loading keeps VGPR < 128) ----
  const float2 Robs = ((const float2*)(p.obs + (size_t)b * 1024))[tid];
  float Rpa = 0.f;
  if (tid < 128) Rpa = p.pol[(size_t)b * 128 + tid];
  else if (tid < 256) Rpa = p.act[(size_t)b * 128 + tid - 128];
  const float Rwzko = p.ko1w[(tid >> 3) * 72 + 64 + (tid & 7)];
  const float Rwzqo = p.qo1w[(tid >> 3) * 72 + 64 + (tid & 7)];
  float4 Rkw1[2], Rqw1[2], Rko1[2];
#pragma unroll
  for (int h = 0; h < 2; h++) {
    const int rq = r8 + 8 * h;
    Rkw1[h] = *(const float4*)(p.kw1w + o * 64 + 4 * rq);
    Rqw1[h] = *(const float4*)(p.qw1w + o * 64 + 4 * rq);
    Rko1[h] = *(const float4*)(p.ko1w + o * 72 + 4 * rq);
  }
  const int bi = (w & 3) * 16 + m;
  const float bias1 = (w < 4 ? p.kw1b : p.qw1b)[bi];
  const float bias2 = (w < 4 ? p.kw2b : p.qw2b)[bi];
  const float bias3 = (w < 4 ? p.ko1b : p.qo1b)[bi];
  const float bias4 = p.ko2b[bi];
  const float Bqo2_0 = p.qo2b[tid & 31];
  const float Bqo2_1 = p.qo2b[(tid & 31) + 32];

  // ---- P0: stage inputs + kw1/qw1 + ko1 ----
  {
    const int e0 = 2 * tid, r0 = e0 >> 6, c0i = e0 & 63;
    const f16 hx = (f16)Robs.x, hy = (f16)Robs.y;
    *(h2*)(s.obsh + r0 * 72 + c0i) = h2{hx, hy};
    *(h2*)(s.u.f.obsl + r0 * 72 + c0i) = h2{(f16)(Robs.x - (float)hx), (f16)(Robs.y - (float)hy)};
  }
  if (tid < 128) s.pi[tid] = Rpa;
  else if (tid < 256) s.act[tid - 128] = Rpa;
  s.u.f.wz[tid] = Rwzko;
  putP(s.u.f.Wp1, Rkw1[0], o, r8); putP(s.u.f.Wp1, Rkw1[1], o, r8 + 8);
  putP(s.u.f.Wp2, Rqw1[0], o, r8); putP(s.u.f.Wp2, Rqw1[1], o, r8 + 8);
  putW(s.u.f.Wxh, s.u.f.Wxl, Rko1[0], o, r8); putW(s.u.f.Wxh, s.u.f.Wxl, Rko1[1], o, r8 + 8);
  __syncthreads();

  // ---- P1: dual hidden (waves 0-3 kw1, 4-7 qw1); issue kw2/qw2 loads ----
  float4 Rkw2[2], Rqw2[2];
#pragma unroll
  for (int h = 0; h < 2; h++) {
    const int rq = r8 + 8 * h;
    Rkw2[h] = *(const float4*)(p.kw2w + o * 64 + 4 * rq);
    Rqw2[h] = *(const float4*)(p.qw2w + o * 64 + 4 * rq);
  }
  {
    const f16* Wp = (w < 4) ? s.u.f.Wp1 : s.u.f.Wp2;
    f16* Xo = (w < 4) ? s.u.f.X1h : s.u.f.X2h;
    v4f a = gemm_plain(s.obsh, Wp, bias1, w & 3, lane);
#pragma unroll
    for (int reg = 0; reg < 4; reg++)
      Xo[(quad * 4 + reg) * 72 + (w & 3) * 16 + m] = (f16)lrelu(a[reg]);
  }
  __syncthreads();
  putP(s.u.f.Wp1, Rkw2[0], o, r8); putP(s.u.f.Wp1, Rkw2[1], o, r8 + 8);
  putP(s.u.f.Wp2, Rqw2[0], o, r8); putP(s.u.f.Wp2, Rqw2[1], o, r8 + 8);
  __syncthreads();

  // ---- P3: key_z / query_z; issue qo1 loads ----
  float4 Rqo1[2];
#pragma unroll
  for (int h = 0; h < 2; h++)
    Rqo1[h] = *(const float4*)(p.qo1w + o * 72 + 4 * (r8 + 8 * h));
  {
    const f16* Wp = (w < 4) ? s.u.f.Wp1 : s.u.f.Wp2;
    const f16* Xi = (w < 4) ? s.u.f.X1h : s.u.f.X2h;
    float* So = (w < 4) ? s.u.f.S2 : s.u.f.S3G;
    v4f a = gemm_plain(Xi, Wp, bias2, w & 3, lane);
#pragma unroll
    for (int reg = 0; reg < 4; reg++)
      So[(quad * 4 + reg) * 68 + (w & 3) * 16 + m] = a[reg];
  }
  __syncthreads();

  // ---- P4: score + sigmoid ; stage Wp=qo1 hi/lo ----
  {
    const int idx = tid >> 1, g2 = tid & 1;
    const int i = idx >> 4, j = idx & 15;
    float a0 = 0.f, a1 = 0.f, a2 = 0.f, a3 = 0.f;
#pragma unroll
    for (int t4 = 0; t4 < 8; t4++) {
      const float4 qv = *(const float4*)(s.u.f.S3G + i * 68 + g2 * 32 + 4 * t4);
      const float4 kv = *(const float4*)(s.u.f.S2 + j * 68 + g2 * 32 + 4 * t4);
      a0 += qv.x * kv.x; a1 += qv.y * kv.y; a2 += qv.z * kv.z; a3 += qv.w * kv.w;
    }
    float sc = (a0 + a1) + (a2 + a3);
    sc += __shfl_xor(sc, 1);
    if (g2 == 0) {
      const float wv = 1.f / (1.f + __expf(-sc * 0.125f));
      s.wsig[idx] = wv;
      p.out1[(size_t)b * 256 + idx] = wv;
    }
    putW(s.u.f.Wp1, s.u.f.Wp2, Rqo1[0], o, r8);
    putW(s.u.f.Wp1, s.u.f.Wp2, Rqo1[1], o, r8 + 8);
  }
  __syncthreads();

  // ---- P5: ko1-hid (waves 0-3) ; Gqo (waves 4-7); issue ko2/qo2T loads ----
  float4 Rko2[2], Rqo2[2];
#pragma unroll
  for (int h = 0; h < 2; h++) {
    const int rq = r8 + 8 * h;
    Rko2[h] = *(const float4*)(p.ko2w + o * 64 + 4 * rq);
    Rqo2[h].x = p.qo2w[(4 * rq + 0) * 64 + o];
    Rqo2[h].y = p.qo2w[(4 * rq + 1) * 64 + o];
    Rqo2[h].z = p.qo2w[(4 * rq + 2) * 64 + o];
    Rqo2[h].w = p.qo2w[(4 * rq + 3) * 64 + o];
  }
  if (w < 4) {
    v4f a = gemm_tile(s.obsh, s.u.f.obsl, s.u.f.Wxh, s.u.f.Wxl, bias3, w, lane);
    const int oo = w * 16 + m;
    float wzv[8];
    *(float4*)wzv = *(const float4*)(s.u.f.wz + oo * 8);
    *(float4*)(wzv + 4) = *(const float4*)(s.u.f.wz + oo * 8 + 4);
#pragma unroll
    for (int reg = 0; reg < 4; reg++) {
      const int rr = quad * 4 + reg;
      const float wrr = s.wsig[rr * 16 + rr];
      float zp = 0.f;
#pragma unroll
      for (int c = 0; c < 8; c++) {
        const float zc = s.pi[rr * 8 + c] + wrr * (s.act[rr * 8 + c] - s.pi[rr * 8 + c]);
        zp += wzv[c] * zc;
      }
      const float y = lrelu(a[reg] + zp);
      const f16 yh = (f16)y;
      s.u.f.X2h[rr * 72 + oo] = yh;
      s.u.f.X2l[rr * 72 + oo] = (f16)(y - (float)yh);
    }
  } else {
    v4f a = gemm_tile(s.obsh, s.u.f.obsl, s.u.f.Wp1, s.u.f.Wp2, bias3, w - 4, lane);
#pragma unroll
    for (int reg = 0; reg < 4; reg++)
      s.u.f.S3G[m * 68 + (quad * 4 + reg) * 4 + (w - 4)] = a[reg];
  }
  __syncthreads();

  // ---- P6: restage Wx=ko2, Wp=qo2T, wz=wzqo ----
  putW(s.u.f.Wxh, s.u.f.Wxl, Rko2[0], o, r8); putW(s.u.f.Wxh, s.u.f.Wxl, Rko2[1], o, r8 + 8);
  putW(s.u.f.Wp1, s.u.f.Wp2, Rqo2[0], o, r8); putW(s.u.f.Wp1, s.u.f.Wp2, Rqo2[1], o, r8 + 8);
  { const int oo = tid >> 3, c = tid & 7; s.u.f.wz[(oo & 15) * 32 + (oo >> 4) * 8 + c] = Rwzqo; }
  __syncthreads();

  // ---- P7: key_o -> X1 ----
  if (w < 4) {
    v4f a = gemm_tile(s.u.f.X2h, s.u.f.X2l, s.u.f.Wxh, s.u.f.Wxl, bias4, w, lane);
    writeX(s.u.f.X1h, s.u.f.X1l, a, w, lane, false);
  }
  __syncthreads();

  // ---- P8: ck -> S2 ; c0 ----
  if (w < 4) {
    v4f a = gemm_tile(s.u.f.X1h, s.u.f.X1l, s.u.f.Wp1, s.u.f.Wp2, 0.f, w, lane);
#pragma unroll
    for (int reg = 0; reg < 4; reg++)
      s.u.f.S2[(quad * 4 + reg) * 68 + w * 16 + m] = a[reg];
  }
  {
    const int rr = tid >> 5, cc = tid & 31;
    const float kv0 = (float)s.u.f.X1h[rr * 72 + cc] + (float)s.u.f.X1l[rr * 72 + cc];
    const float kv1 = (float)s.u.f.X1h[rr * 72 + cc + 32] + (float)s.u.f.X1l[rr * 72 + cc + 32];
    float t = kv0 * Bqo2_0 + kv1 * Bqo2_1;
#pragma unroll
    for (int mk = 1; mk < 32; mk <<= 1) t += __shfl_xor(t, mk);
    if (cc == 0) s.c0[rr] = t;
  }
  __syncthreads();

  // ---- P9: qo-score -> e ; issue av/fv2/back-bias loads ----
  const float4 rav1a = ((const float4*)p.av1w)[tid * 2];
  const float4 rav1b = ((const float4*)p.av1w)[tid * 2 + 1];
  const float rav1c = p.av1w[4096 + tid];
  const float4 rav2a = ((const float4*)p.av2w)[tid * 2];
  const float4 rav2b = ((const float4*)p.av2w)[tid * 2 + 1];
  const float rfv2 = p.fv2w[tid];
  float rb1 = 0.f, rb2 = 0.f, rb3 = 0.f, rb4 = 0.f;
  if (tid < 64) { rb1 = p.av1b[tid]; rb2 = p.av2b[tid]; rb3 = p.fv1b[tid]; }
  if (tid < 8) rb4 = p.fv2b[tid];
  {
    const int idx = tid >> 1, g2 = tid & 1;
    const int i = idx >> 4, j = idx & 15;
    const float wij = s.wsig[i * 16 + j];
    float z[8];
#pragma unroll
    for (int c = 0; c < 8; c++) z[c] = s.pi[j * 8 + c] + wij * (s.act[j * 8 + c] - s.pi[j * 8 + c]);
    float sc = 0.f;
#pragma unroll
    for (int gg = 2 * g2; gg <= 2 * g2 + 1; gg++) {
#pragma unroll
      for (int t = 0; t < 16; t++) {
        const float4 wa = *(const float4*)(s.u.f.wz + t * 32 + gg * 8);
        const float4 wb = *(const float4*)(s.u.f.wz + t * 32 + gg * 8 + 4);
        float hv = s.u.f.S3G[t * 68 + j * 4 + gg]
          + wa.x * z[0] + wa.y * z[1] + wa.z * z[2] + wa.w * z[3]
          + wb.x * z[4] + wb.y * z[5] + wb.z * z[6] + wb.w * z[7];
        hv = lrelu(hv);
        sc += s.u.f.S2[i * 68 + gg * 16 + t] * hv;
      }
    }
    sc += __shfl_xor(sc, 1);
    if (g2 == 0) {
      float yv = (sc + s.c0[i]) * 0.125f;
      yv = fminf(fmaxf(yv, -5.f), 5.f);
      s.eh[idx] = (f16)__expf(yv);
    }
  }
  __syncthreads();

  // ---- P10a: softmax -> wo ; stage back weights ----
  if (tid < 256) {
    const int i = tid >> 4, j = tid & 15;
    float ev[16]; float mx = -1e30f;
#pragma unroll
    for (int jj = 0; jj < 16; jj++) { ev[jj] = (float)s.eh[i * 16 + jj]; mx = fmaxf(mx, ev[jj]); }
    float den = 0.f;
#pragma unroll
    for (int jj = 0; jj < 16; jj++) den += __expf(ev[jj] - mx);
    s.wo[tid] = __expf(ev[j] - mx) / den;
  }
  {
    float av1v[8] = {rav1a.x, rav1a.y, rav1a.z, rav1a.w, rav1b.x, rav1b.y, rav1b.z, rav1b.w};
#pragma unroll
    for (int e = 0; e < 8; e++) {
      const int k = tid * 8 + e, rr = k / 72, cc = k - rr * 72;
      s.u.bk.W.av.av1H[rr * 96 + cc] = (f16)av1v[e];
    }
    const int k = 4096 + tid, rr = k / 72, cc = k - rr * 72;
    s.u.bk.W.av.av1H[rr * 96 + cc] = (f16)rav1c;
    const int row = tid >> 3, c0p = 72 + (tid & 7) * 3;
#pragma unroll
    for (int c = 0; c < 3; c++) s.u.bk.W.av.av1H[row * 96 + c0p + c] = (f16)0.f;
    float av2v[8] = {rav2a.x, rav2a.y, rav2a.z, rav2a.w, rav2b.x, rav2b.y, rav2b.z, rav2b.w};
#pragma unroll
    for (int e = 0; e < 8; e++) {
      const int k2 = tid * 8 + e;
      s.u.bk.W.av.av2H[(k2 >> 6) * 72 + (k2 & 63)] = (f16)av2v[e];
    }
    s.u.bk.fv2pw[tid] = (f16)rfv2;
    if (tid < 64) { s.u.bk.av1b[tid] = rb1; s.u.bk.av2b[tid] = rb2; s.u.bk.fv1b[tid] = rb3; }
    if (tid < 8) s.u.bk.fv2b[tid] = rb4;
  }
  __syncthreads();

  // ---- P10b: AextH + out2 ----
  {
    const int kk = tid >> 5, j2 = tid & 31;
    float v = 0.f;
    if (j2 < 16) v = s.wo[kk * 16 + j2] * 0.0625f;
    else if (j2 - 16 == kk) v = s.wo[kk * 16 + kk] * 0.0625f;
    s.u.bk.AextH[kk * 40 + j2] = (f16)v;
    const int q_ = tid >> 1, g2_ = tid & 1, k_ = q_ & 15;
    float* dst = p.out2 + ((size_t)b * 256 + q_) * 16 + 8 * g2_;
    *(float4*)(dst) = *(const float4*)(s.wo + k_ * 16 + 8 * g2_);
    *(float4*)(dst + 4) = *(const float4*)(s.wo + k_ * 16 + 8 * g2_ + 4);
  }
  __syncthreads();

  // ---- P11: AO (waves 0-3, i=iq*4+w) + AP (wave 4) + attn_src (wave 5); issue fv1 loads ----
  float4 rfv[4];
#pragma unroll
  for (int qq = 0; qq < 4; qq++) rfv[qq] = ((const float4*)p.fv1w)[tid * 4 + qq];
  const int i_ = iq * 4 + w;
  f16* Sl = &s.u.bk.slice[w & 3][0];
  if (w < 4) {
    v8h az = {};
    if (quad == 0) {
      const float wv = s.wsig[i_ * 16 + m];
#pragma unroll
      for (int c = 0; c < 8; c++)
        az[c] = (f16)(s.pi[m * 8 + c] + wv * (s.act[m * 8 + c] - s.pi[m * 8 + c]));
    }
    v4f acc2[4];
    av_mlp2(s.obsh, s.u.bk.W.av.av1H, s.u.bk.W.av.av2H, s.u.bk.av1b, s.u.bk.av2b, Sl, az, lane, acc2);
#pragma unroll
    for (int nt = 0; nt < 4; nt++)
#pragma unroll
      for (int reg = 0; reg < 4; reg++)
        Sl[(nt * 16 + m) * 24 + quad * 4 + reg] = (f16)acc2[nt][reg];
  }
  if (w == 4) {
    v8h az = {};
    if (quad == 0) {
#pragma unroll
      for (int c = 0; c < 8; c++) az[c] = (f16)s.pi[m * 8 + c];
    }
    v4f acc2[4];
    av_mlp2(s.obsh, s.u.bk.W.av.av1H, s.u.bk.W.av.av2H, s.u.bk.av1b, s.u.bk.av2b, s.u.bk.APT, az, lane, acc2);
#pragma unroll
    for (int nt = 0; nt < 4; nt++)
#pragma unroll
      for (int reg = 0; reg < 4; reg++)
        s.u.bk.APT[(nt * 16 + m) * 24 + quad * 4 + reg] = (f16)acc2[nt][reg];
  }
  if (w == 5) {
    v8h az = {};
    if (quad == 0) {
      const float wv = s.wsig[m * 16 + m];
#pragma unroll
      for (int c = 0; c < 8; c++)
        az[c] = (f16)(s.pi[m * 8 + c] + wv * (s.act[m * 8 + c] - s.pi[m * 8 + c]));
    }
    v4f acc2[4];
    av_mlp2(s.obsh, s.u.bk.W.av.av1H, s.u.bk.W.av.av2H, s.u.bk.av1b, s.u.bk.av2b, s.u.bk.AOsrcD, az, lane, acc2);
#pragma unroll
    for (int nt = 0; nt < 4; nt++)
#pragma unroll
      for (int reg = 0; reg < 4; reg++)
        s.u.bk.AOsrcD[(quad * 4 + reg) * 72 + nt * 16 + m] = (f16)acc2[nt][reg];
  }
  __syncthreads();

  // ---- P12: fv1H from registers ----
#pragma unroll
  for (int qq = 0; qq < 4; qq++) {
    const int e0 = tid * 16 + qq * 4;
    h2* d = (h2*)&s.u.bk.W.fv1H[(e0 >> 7) * 136 + (e0 & 127)];
    d[0] = h2{(f16)rfv[qq].x, (f16)rfv[qq].y};
    d[1] = h2{(f16)rfv[qq].z, (f16)rfv[qq].w};
  }
  __syncthreads();

  // ---- P13: mixed + fv1 + fv2 + out0 (waves 0-3) ----
  if (w < 4) {
    {
      const v8h am = *(const v8h*)(&s.u.bk.AextH[m * 40 + quad * 8]);
      v4f macc[4];
#pragma unroll
      for (int nt = 0; nt < 4; nt++) {
        const int oo = nt * 16 + m;
        v8h bf;
        if (quad < 2) {
          bf = *(const v8h*)(Sl + oo * 24 + quad * 8);
        } else {
          const v8h apv = *(const v8h*)(&s.u.bk.APT[oo * 24 + (quad - 2) * 8]);
          const v8h aov = *(const v8h*)(Sl + oo * 24 + (quad - 2) * 8);
          bf = apv - aov;
        }
        v4f z4 = {0.f, 0.f, 0.f, 0.f};
        macc[nt] = __builtin_amdgcn_mfma_f32_16x16x32_f16(am, bf, z4, 0, 0, 0);
      }
#pragma unroll
      for (int nt = 0; nt < 4; nt++)
#pragma unroll
        for (int reg = 0; reg < 4; reg++)
          Sl[(quad * 4 + reg) * 72 + nt * 16 + m] = (f16)macc[nt][reg];
    }
    {
      const v8h f0 = *(const v8h*)(&s.u.bk.AOsrcD[m * 72 + quad * 8]);
      const v8h f1 = *(const v8h*)(&s.u.bk.AOsrcD[m * 72 + 32 + quad * 8]);
      const v8h f2 = *(const v8h*)(Sl + m * 72 + quad * 8);
      const v8h f3 = *(const v8h*)(Sl + m * 72 + 32 + quad * 8);
#pragma unroll
      for (int nt = 0; nt < 4; nt++) {
        const float bv = s.u.bk.fv1b[nt * 16 + m];
        v4f acc = {bv, bv, bv, bv};
        acc = __builtin_amdgcn_mfma_f32_16x16x32_f16(f0, bfrag(s.u.bk.W.fv1H, 136, nt, 0, lane), acc, 0, 0, 0);
        acc = __builtin_amdgcn_mfma_f32_16x16x32_f16(f1, bfrag(s.u.bk.W.fv1H, 136, nt, 1, lane), acc, 0, 0, 0);
        acc = __builtin_amdgcn_mfma_f32_16x16x32_f16(f2, bfrag(s.u.bk.W.fv1H, 136, nt, 2, lane), acc, 0, 0, 0);
        acc = __builtin_amdgcn_mfma_f32_16x16x32_f16(f3, bfrag(s.u.bk.W.fv1H, 136, nt, 3, lane), acc, 0, 0, 0);
#pragma unroll
        for (int reg = 0; reg < 4; reg++)
          Sl[(quad * 4 + reg) * 72 + nt * 16 + m] = (f16)lrelu(acc[reg]);
      }
    }
    {
      const int g2 = quad;
      float y0 = s.u.bk.fv2b[2 * g2], y1 = s.u.bk.fv2b[2 * g2 + 1];
#pragma unroll
      for (int o2 = 0; o2 < 32; o2++) {
        const h2 hh = *(const h2*)(Sl + m * 72 + 2 * o2);
        const h2 w0 = *(const h2*)(&s.u.bk.fv2pw[(2 * g2) * 64 + 2 * o2]);
        const h2 w1 = *(const h2*)(&s.u.bk.fv2pw[(2 * g2 + 1) * 64 + 2 * o2]);
        y0 = fdot2f(w0, hh, y0);
        y1 = fdot2f(w1, hh, y1);
      }
      *(float2*)(p.out0 + ((size_t)b * 256 + i_ * 16 + m) * 8 + 2 * g2) = make_float2(y0, y1);
    }
  }
}

extern "C" void kernel_launch(void* const* d_in, const int* in_sizes, int n_in,
                              void* d_out, int out_size, void* d_ws, size_t ws_size,
                              hipStream_t stream) {
  P p;
  p.obs = (const float*)d_in[0];
  p.pol = (const float*)d_in[1];
  p.act = (const float*)d_in[2];
  p.kw1w = (const float*)d_in[3];  p.kw1b = (const float*)d_in[4];
  p.kw2w = (const float*)d_in[5];  p.kw2b = (const float*)d_in[6];
  p.qw1w = (const float*)d_in[7];  p.qw1b = (const float*)d_in[8];
  p.qw2w = (const float*)d_in[9];  p.qw2b = (const float*)d_in[10];
  p.ko1w = (const float*)d_in[11]; p.ko1b = (const float*)d_in[12];
  p.ko2w = (const float*)d_in[13]; p.ko2b = (const float*)d_in[14];
  p.qo1w = (const float*)d_in[15]; p.qo1b = (const float*)d_in[16];
  p.qo2w = (const float*)d_in[17]; p.qo2b = (const float*)d_in[18];
  p.av1w = (const float*)d_in[19]; p.av1b = (const float*)d_in[20];
  p.av2w = (const float*)d_in[21]; p.av2b = (const float*)d_in[22];
  p.fv1w = (const float*)d_in[23]; p.fv1b = (const float*)d_in[24];
  p.fv2w = (const float*)d_in[25]; p.fv2b = (const float*)d_in[26];

  const int Bn = in_sizes[0] / (A_ * DOBS_);   // 128
  p.out0 = (float*)d_out;
  p.out1 = p.out0 + (size_t)Bn * A_ * A_ * NA_;
  p.out2 = p.out1 + (size_t)Bn * A_ * A_;

  hipLaunchKernelGGL(critic_fused, dim3(4 * Bn), dim3(512), 0, stream, p);
}

// Round 8
// 125.324 us; speedup vs baseline: 1.1096x; 1.1096x over previous
//
#include <hip/hip_runtime.h>

#define A_ 16
#define NA_ 8
#define DOBS_ 64

typedef _Float16 f16;
typedef f16 h2 __attribute__((ext_vector_type(2)));
typedef f16 v8h __attribute__((ext_vector_type(8)));
typedef float v4f __attribute__((ext_vector_type(4)));

__device__ __forceinline__ float fdot2f(h2 a, h2 b, float c) {
  return __builtin_amdgcn_fdot2(a, b, c, false);
}
__device__ __forceinline__ float lrelu(float x) { return x > 0.f ? x : 0.01f * x; }

struct P {
  const float *obs, *pol, *act;
  const float *kw1w, *kw1b, *kw2w, *kw2b, *qw1w, *qw1b, *qw2w, *qw2b;
  const float *ko1w, *ko1b, *ko2w, *ko2b, *qo1w, *qo1b, *qo2w, *qo2b;
  const float *av1w, *av1b, *av2w, *av2b, *fv1w, *fv1b, *fv2w, *fv2b;
  float *out0, *out1, *out2;
};

// ---------- dynamic-LDS memory map (f16 offsets) ----------
#define OBSH 0
#define OBSL 1152
#define X1Ho 2304
#define X1Lo 3456
#define X2Ho 4608
#define X2Lo 5760
#define EHO  6912
#define FLT  7168      // float region starts here (f16 units)
#define F_PI   0
#define F_ACT  128
#define F_WSIG 256
#define F_WO   512
#define F_C0   768
#define F_S2   784
#define F_S3G  1872
#define F_WZK  2960
#define F_WZQ  3472    // float region = 3984 floats = 7968 f16
#define WKW1  15136
#define WQW1  19744
#define WKW2  24352
#define WQW2  28960
#define WKO1H 33568
#define WKO1L 38176
#define WKO2H 42784
#define WKO2L 47392
#define WQO1H 52000
#define WQO1L 56608
#define WQO2H 61216
#define WQO2L 65824
#define LDS_F16 70432  // 140864 bytes
// back overlays (dead-slot reuse)
#define AV1H  15136    // over kw1/qw1 (dead after P1/P2)
#define AV2H  21280
#define FV1H  25888
#define FV2PW 34592
#define BACKB 35104    // 200 floats
#define SLICE 52000    // over qo1 h/l + qo2h (dead after P4/P6)
#define AOSRC 64288
#define APTO  65440
#define AEXT  66976

__device__ __forceinline__ v4f gemm_plain(const f16* Xh, const f16* W, float bv, int nt, int lane) {
  const int m = lane & 15, q = lane >> 4;
  v4f acc = {bv, bv, bv, bv};
  const v8h a0 = *(const v8h*)(Xh + m * 72 + q * 8);
  const v8h a1 = *(const v8h*)(Xh + m * 72 + 32 + q * 8);
  const f16* wr = W + (nt * 16 + m) * 72 + q * 8;
  acc = __builtin_amdgcn_mfma_f32_16x16x32_f16(a0, *(const v8h*)wr, acc, 0, 0, 0);
  acc = __builtin_amdgcn_mfma_f32_16x16x32_f16(a1, *(const v8h*)(wr + 32), acc, 0, 0, 0);
  return acc;
}

__device__ __forceinline__ v4f gemm_tile(const f16* Xh, const f16* Xl,
                                         const f16* Wh, const f16* Wl,
                                         float bv, int nt, int lane) {
  const int m = lane & 15, q = lane >> 4;
  v4f acc = {bv, bv, bv, bv};
  const v8h ah0 = *(const v8h*)(Xh + m * 72 + q * 8);
  const v8h ah1 = *(const v8h*)(Xh + m * 72 + 32 + q * 8);
  const v8h al0 = *(const v8h*)(Xl + m * 72 + q * 8);
  const v8h al1 = *(const v8h*)(Xl + m * 72 + 32 + q * 8);
  const f16* wr = Wh + (nt * 16 + m) * 72 + q * 8;
  const v8h bh0 = *(const v8h*)(wr);
  const v8h bh1 = *(const v8h*)(wr + 32);
  const f16* wr2 = Wl + (nt * 16 + m) * 72 + q * 8;
  const v8h bl0 = *(const v8h*)(wr2);
  const v8h bl1 = *(const v8h*)(wr2 + 32);
  acc = __builtin_amdgcn_mfma_f32_16x16x32_f16(ah0, bh0, acc, 0, 0, 0);
  acc = __builtin_amdgcn_mfma_f32_16x16x32_f16(ah1, bh1, acc, 0, 0, 0);
  acc = __builtin_amdgcn_mfma_f32_16x16x32_f16(ah0, bl0, acc, 0, 0, 0);
  acc = __builtin_amdgcn_mfma_f32_16x16x32_f16(ah1, bl1, acc, 0, 0, 0);
  acc = __builtin_amdgcn_mfma_f32_16x16x32_f16(al0, bh0, acc, 0, 0, 0);
  acc = __builtin_amdgcn_mfma_f32_16x16x32_f16(al1, bh1, acc, 0, 0, 0);
  return acc;
}

__device__ __forceinline__ void writeX(f16* Xh, f16* Xl, v4f acc, int nt, int lane, bool relu) {
  const int m = lane & 15, q = lane >> 4;
#pragma unroll
  for (int reg = 0; reg < 4; reg++) {
    float y = acc[reg];
    if (relu) y = lrelu(y);
    const f16 yh = (f16)y;
    Xh[(q * 4 + reg) * 72 + nt * 16 + m] = yh;
    Xl[(q * 4 + reg) * 72 + nt * 16 + m] = (f16)(y - (float)yh);
  }
}

__device__ __forceinline__ void putP(f16* W, float4 v, int o, int rq) {
  h2* d = (h2*)(W + o * 72 + 4 * rq);
  d[0] = h2{(f16)v.x, (f16)v.y};
  d[1] = h2{(f16)v.z, (f16)v.w};
}

__device__ __forceinline__ void putW(f16* Wh, f16* Wl, float4 v, int o, int rq) {
  h2* dh = (h2*)(Wh + o * 72 + 4 * rq);
  h2* dl = (h2*)(Wl + o * 72 + 4 * rq);
  const f16 hx = (f16)v.x, hy = (f16)v.y, hz = (f16)v.z, hw = (f16)v.w;
  dh[0] = h2{hx, hy};
  dh[1] = h2{hz, hw};
  dl[0] = h2{(f16)(v.x - (float)hx), (f16)(v.y - (float)hy)};
  dl[1] = h2{(f16)(v.z - (float)hz), (f16)(v.w - (float)hw)};
}

__device__ __forceinline__ v8h bfrag(const f16* Wm, int stride, int nt, int ks, int lane) {
  const int n = lane & 15, q = lane >> 4;
  return *(const v8h*)(Wm + (nt * 16 + n) * stride + ks * 32 + q * 8);
}

__device__ __forceinline__ void av_mlp2(const f16* obsh, const f16* av1H, const f16* av2H,
                                        const float* av1b, const float* av2b,
                                        f16* Hbuf, v8h az, int lane, v4f acc2[4]) {
  const int m = lane & 15, q = lane >> 4;
  const v8h a0 = *(const v8h*)(obsh + m * 72 + q * 8);
  const v8h a1 = *(const v8h*)(obsh + m * 72 + 32 + q * 8);
#pragma unroll
  for (int nt = 0; nt < 4; nt++) {
    const float bv = av1b[nt * 16 + m];
    v4f acc = {bv, bv, bv, bv};
    acc = __builtin_amdgcn_mfma_f32_16x16x32_f16(a0, bfrag(av1H, 96, nt, 0, lane), acc, 0, 0, 0);
    acc = __builtin_amdgcn_mfma_f32_16x16x32_f16(a1, bfrag(av1H, 96, nt, 1, lane), acc, 0, 0, 0);
    acc = __builtin_amdgcn_mfma_f32_16x16x32_f16(az, bfrag(av1H, 96, nt, 2, lane), acc, 0, 0, 0);
#pragma unroll
    for (int reg = 0; reg < 4; reg++)
      Hbuf[(q * 4 + reg) * 72 + nt * 16 + m] = (f16)lrelu(acc[reg]);
  }
  const v8h h0 = *(const v8h*)(Hbuf + m * 72 + q * 8);
  const v8h h1 = *(const v8h*)(Hbuf + m * 72 + 32 + q * 8);
#pragma unroll
  for (int nt = 0; nt < 4; nt++) {
    const float bv = av2b[nt * 16 + m];
    v4f acc = {bv, bv, bv, bv};
    acc = __builtin_amdgcn_mfma_f32_16x16x32_f16(h0, bfrag(av2H, 72, nt, 0, lane), acc, 0, 0, 0);
    acc = __builtin_amdgcn_mfma_f32_16x16x32_f16(h1, bfrag(av2H, 72, nt, 1, lane), acc, 0, 0, 0);
    acc2[nt] = acc;
  }
}

__global__ __launch_bounds__(512) void critic_fused(P p) {
  extern __shared__ f16 SMB[];
  float* F = (float*)(SMB + FLT);
  const int tid = threadIdx.x;
  const int b = blockIdx.x >> 1, ihalf = blockIdx.x & 1;
  const int w = tid >> 6, lane = tid & 63;
  const int m = lane & 15, quad = lane >> 4;
  const int o = tid & 63, r8 = tid >> 6;

  // ---- t0: load ALL front weights + inputs (single global-latency exposure) ----
  const float2 Robs = ((const float2*)(p.obs + (size_t)b * 1024))[tid];
  float Rpa = 0.f;
  if (tid < 128) Rpa = p.pol[(size_t)b * 128 + tid];
  else if (tid < 256) Rpa = p.act[(size_t)b * 128 + tid - 128];
  const float Rwzko = p.ko1w[(tid >> 3) * 72 + 64 + (tid & 7)];
  const float Rwzqo = p.qo1w[(tid >> 3) * 72 + 64 + (tid & 7)];
  float4 Rkw1[2], Rqw1[2], Rkw2[2], Rqw2[2], Rko1[2], Rko2[2], Rqo1[2], Rqo2[2];
#pragma unroll
  for (int h = 0; h < 2; h++) {
    const int rq = r8 + 8 * h;
    Rkw1[h] = *(const float4*)(p.kw1w + o * 64 + 4 * rq);
    Rqw1[h] = *(const float4*)(p.qw1w + o * 64 + 4 * rq);
    Rkw2[h] = *(const float4*)(p.kw2w + o * 64 + 4 * rq);
    Rqw2[h] = *(const float4*)(p.qw2w + o * 64 + 4 * rq);
    Rko1[h] = *(const float4*)(p.ko1w + o * 72 + 4 * rq);
    Rko2[h] = *(const float4*)(p.ko2w + o * 64 + 4 * rq);
    Rqo1[h] = *(const float4*)(p.qo1w + o * 72 + 4 * rq);
    Rqo2[h].x = p.qo2w[(4 * rq + 0) * 64 + o];
    Rqo2[h].y = p.qo2w[(4 * rq + 1) * 64 + o];
    Rqo2[h].z = p.qo2w[(4 * rq + 2) * 64 + o];
    Rqo2[h].w = p.qo2w[(4 * rq + 3) * 64 + o];
  }
  const int bi = (w & 3) * 16 + m;
  const float bias1 = (w < 4 ? p.kw1b : p.qw1b)[bi];
  const float bias2 = (w < 4 ? p.kw2b : p.qw2b)[bi];
  const float bias3 = (w < 4 ? p.ko1b : p.qo1b)[bi];
  const float bias4 = p.ko2b[bi];
  const float Bqo2_0 = p.qo2b[tid & 31];
  const float Bqo2_1 = p.qo2b[(tid & 31) + 32];

  // ---- P0: stage everything front ----
  {
    const int e0 = 2 * tid, r0 = e0 >> 6, c0i = e0 & 63;
    const f16 hx = (f16)Robs.x, hy = (f16)Robs.y;
    *(h2*)(SMB + OBSH + r0 * 72 + c0i) = h2{hx, hy};
    *(h2*)(SMB + OBSL + r0 * 72 + c0i) = h2{(f16)(Robs.x - (float)hx), (f16)(Robs.y - (float)hy)};
  }
  if (tid < 128) F[F_PI + tid] = Rpa;
  else if (tid < 256) F[F_ACT + tid - 128] = Rpa;
  F[F_WZK + tid] = Rwzko;
  { const int oo = tid >> 3, c = tid & 7; F[F_WZQ + (oo & 15) * 32 + (oo >> 4) * 8 + c] = Rwzqo; }
#pragma unroll
  for (int h = 0; h < 2; h++) {
    const int rq = r8 + 8 * h;
    putP(SMB + WKW1, Rkw1[h], o, rq);
    putP(SMB + WQW1, Rqw1[h], o, rq);
    putP(SMB + WKW2, Rkw2[h], o, rq);
    putP(SMB + WQW2, Rqw2[h], o, rq);
    putW(SMB + WKO1H, SMB + WKO1L, Rko1[h], o, rq);
    putW(SMB + WKO2H, SMB + WKO2L, Rko2[h], o, rq);
    putW(SMB + WQO1H, SMB + WQO1L, Rqo1[h], o, rq);
    putW(SMB + WQO2H, SMB + WQO2L, Rqo2[h], o, rq);
  }
  __syncthreads();

  // ---- P1: dual hidden (w0-3 kw1 -> X1h, w4-7 qw1 -> X2h) ----
  {
    const f16* Wp = (w < 4) ? (SMB + WKW1) : (SMB + WQW1);
    f16* Xo = (w < 4) ? (SMB + X1Ho) : (SMB + X2Ho);
    v4f a = gemm_plain(SMB + OBSH, Wp, bias1, w & 3, lane);
#pragma unroll
    for (int reg = 0; reg < 4; reg++)
      Xo[(quad * 4 + reg) * 72 + (w & 3) * 16 + m] = (f16)lrelu(a[reg]);
  }
  __syncthreads();

  // ---- P2: key_z -> S2 (w0-3), query_z -> S3G (w4-7) ----
  {
    const f16* Wp = (w < 4) ? (SMB + WKW2) : (SMB + WQW2);
    const f16* Xi = (w < 4) ? (SMB + X1Ho) : (SMB + X2Ho);
    float* So = (w < 4) ? (F + F_S2) : (F + F_S3G);
    v4f a = gemm_plain(Xi, Wp, bias2, w & 3, lane);
#pragma unroll
    for (int reg = 0; reg < 4; reg++)
      So[(quad * 4 + reg) * 68 + (w & 3) * 16 + m] = a[reg];
  }
  __syncthreads();

  // ---- P3: score + sigmoid + out1 ----
  {
    const int idx = tid >> 1, g2 = tid & 1;
    const int i = idx >> 4, j = idx & 15;
    float a0 = 0.f, a1 = 0.f, a2 = 0.f, a3 = 0.f;
#pragma unroll
    for (int t4 = 0; t4 < 8; t4++) {
      const float4 qv = *(const float4*)(F + F_S3G + i * 68 + g2 * 32 + 4 * t4);
      const float4 kv = *(const float4*)(F + F_S2 + j * 68 + g2 * 32 + 4 * t4);
      a0 += qv.x * kv.x; a1 += qv.y * kv.y; a2 += qv.z * kv.z; a3 += qv.w * kv.w;
    }
    float sc = (a0 + a1) + (a2 + a3);
    sc += __shfl_xor(sc, 1);
    if (g2 == 0) {
      const float wv = 1.f / (1.f + __expf(-sc * 0.125f));
      F[F_WSIG + idx] = wv;
      p.out1[(size_t)b * 256 + idx] = wv;
    }
  }
  __syncthreads();

  // ---- P4: ko1-hid (w0-3) -> X2h/l ; Gqo (w4-7) -> S3G ----
  if (w < 4) {
    v4f a = gemm_tile(SMB + OBSH, SMB + OBSL, SMB + WKO1H, SMB + WKO1L, bias3, w, lane);
    const int oo = w * 16 + m;
    float wzv[8];
    *(float4*)wzv = *(const float4*)(F + F_WZK + oo * 8);
    *(float4*)(wzv + 4) = *(const float4*)(F + F_WZK + oo * 8 + 4);
#pragma unroll
    for (int reg = 0; reg < 4; reg++) {
      const int rr = quad * 4 + reg;
      const float wrr = F[F_WSIG + rr * 16 + rr];
      float zp = 0.f;
#pragma unroll
      for (int c = 0; c < 8; c++) {
        const float zc = F[F_PI + rr * 8 + c] + wrr * (F[F_ACT + rr * 8 + c] - F[F_PI + rr * 8 + c]);
        zp += wzv[c] * zc;
      }
      const float y = lrelu(a[reg] + zp);
      const f16 yh = (f16)y;
      SMB[X2Ho + rr * 72 + oo] = yh;
      SMB[X2Lo + rr * 72 + oo] = (f16)(y - (float)yh);
    }
  } else {
    v4f a = gemm_tile(SMB + OBSH, SMB + OBSL, SMB + WQO1H, SMB + WQO1L, bias3, w - 4, lane);
#pragma unroll
    for (int reg = 0; reg < 4; reg++)
      F[F_S3G + m * 68 + (quad * 4 + reg) * 4 + (w - 4)] = a[reg];
  }
  __syncthreads();

  // ---- P5: key_o -> X1 ; issue av/fv2/back-bias loads ----
  const float4 rav1a = ((const float4*)p.av1w)[tid * 2];
  const float4 rav1b = ((const float4*)p.av1w)[tid * 2 + 1];
  const float rav1c = p.av1w[4096 + tid];
  const float4 rav2a = ((const float4*)p.av2w)[tid * 2];
  const float4 rav2b = ((const float4*)p.av2w)[tid * 2 + 1];
  const float rfv2 = p.fv2w[tid];
  float rb1 = 0.f, rb2 = 0.f, rb3 = 0.f, rb4 = 0.f;
  if (tid < 64) { rb1 = p.av1b[tid]; rb2 = p.av2b[tid]; rb3 = p.fv1b[tid]; }
  if (tid < 8) rb4 = p.fv2b[tid];
  if (w < 4) {
    v4f a = gemm_tile(SMB + X2Ho, SMB + X2Lo, SMB + WKO2H, SMB + WKO2L, bias4, w, lane);
    writeX(SMB + X1Ho, SMB + X1Lo, a, w, lane, false);
  }
  __syncthreads();

  // ---- P6: ck -> S2 ; c0 ; issue fv1 loads ----
  float4 rfv[4];
#pragma unroll
  for (int qq = 0; qq < 4; qq++) rfv[qq] = ((const float4*)p.fv1w)[tid * 4 + qq];
  if (w < 4) {
    v4f a = gemm_tile(SMB + X1Ho, SMB + X1Lo, SMB + WQO2H, SMB + WQO2L, 0.f, w, lane);
#pragma unroll
    for (int reg = 0; reg < 4; reg++)
      F[F_S2 + (quad * 4 + reg) * 68 + w * 16 + m] = a[reg];
  }
  {
    const int rr = tid >> 5, cc = tid & 31;
    const float kv0 = (float)SMB[X1Ho + rr * 72 + cc] + (float)SMB[X1Lo + rr * 72 + cc];
    const float kv1 = (float)SMB[X1Ho + rr * 72 + cc + 32] + (float)SMB[X1Lo + rr * 72 + cc + 32];
    float t = kv0 * Bqo2_0 + kv1 * Bqo2_1;
#pragma unroll
    for (int mk = 1; mk < 32; mk <<= 1) t += __shfl_xor(t, mk);
    if (cc == 0) F[F_C0 + rr] = t;
  }
  __syncthreads();

  // ---- P7: qo-score -> eh ----
  {
    const int idx = tid >> 1, g2 = tid & 1;
    const int i = idx >> 4, j = idx & 15;
    const float wij = F[F_WSIG + i * 16 + j];
    float z[8];
#pragma unroll
    for (int c = 0; c < 8; c++)
      z[c] = F[F_PI + j * 8 + c] + wij * (F[F_ACT + j * 8 + c] - F[F_PI + j * 8 + c]);
    float sc = 0.f;
#pragma unroll
    for (int gg = 2 * g2; gg <= 2 * g2 + 1; gg++) {
#pragma unroll
      for (int t = 0; t < 16; t++) {
        const float4 wa = *(const float4*)(F + F_WZQ + t * 32 + gg * 8);
        const float4 wb = *(const float4*)(F + F_WZQ + t * 32 + gg * 8 + 4);
        float hv = F[F_S3G + t * 68 + j * 4 + gg]
          + wa.x * z[0] + wa.y * z[1] + wa.z * z[2] + wa.w * z[3]
          + wb.x * z[4] + wb.y * z[5] + wb.z * z[6] + wb.w * z[7];
        hv = lrelu(hv);
        sc += F[F_S2 + i * 68 + gg * 16 + t] * hv;
      }
    }
    sc += __shfl_xor(sc, 1);
    if (g2 == 0) {
      float yv = (sc + F[F_C0 + i]) * 0.125f;
      yv = fminf(fmaxf(yv, -5.f), 5.f);
      SMB[EHO + idx] = (f16)__expf(yv);
    }
  }
  __syncthreads();

  // ---- P8: softmax -> wo ; stage back weights into dead slots ----
  if (tid < 256) {
    const int i = tid >> 4, j = tid & 15;
    float ev[16]; float mx = -1e30f;
#pragma unroll
    for (int jj = 0; jj < 16; jj++) { ev[jj] = (float)SMB[EHO + i * 16 + jj]; mx = fmaxf(mx, ev[jj]); }
    float den = 0.f;
#pragma unroll
    for (int jj = 0; jj < 16; jj++) den += __expf(ev[jj] - mx);
    F[F_WO + tid] = __expf(ev[j] - mx) / den;
  }
  {
    float av1v[8] = {rav1a.x, rav1a.y, rav1a.z, rav1a.w, rav1b.x, rav1b.y, rav1b.z, rav1b.w};
#pragma unroll
    for (int e = 0; e < 8; e++) {
      const int k = tid * 8 + e, rr = k / 72, cc = k - rr * 72;
      SMB[AV1H + rr * 96 + cc] = (f16)av1v[e];
    }
    const int k = 4096 + tid, rr = k / 72, cc = k - rr * 72;
    SMB[AV1H + rr * 96 + cc] = (f16)rav1c;
    const int row = tid >> 3, c0p = 72 + (tid & 7) * 3;
#pragma unroll
    for (int c = 0; c < 3; c++) SMB[AV1H + row * 96 + c0p + c] = (f16)0.f;
    float av2v[8] = {rav2a.x, rav2a.y, rav2a.z, rav2a.w, rav2b.x, rav2b.y, rav2b.z, rav2b.w};
#pragma unroll
    for (int e = 0; e < 8; e++) {
      const int k2 = tid * 8 + e;
      SMB[AV2H + (k2 >> 6) * 72 + (k2 & 63)] = (f16)av2v[e];
    }
    SMB[FV2PW + tid] = (f16)rfv2;
    float* BF = (float*)(SMB + BACKB);
    if (tid < 64) { BF[tid] = rb1; BF[64 + tid] = rb2; BF[128 + tid] = rb3; }
    if (tid < 8) BF[192 + tid] = rb4;
  }
  __syncthreads();

  // ---- P9: AextH + out2 ----
  {
    const int kk = tid >> 5, j2 = tid & 31;
    float v = 0.f;
    if (j2 < 16) v = F[F_WO + kk * 16 + j2] * 0.0625f;
    else if (j2 - 16 == kk) v = F[F_WO + kk * 16 + kk] * 0.0625f;
    SMB[AEXT + kk * 40 + j2] = (f16)v;
    const int q_ = tid >> 1, g2_ = tid & 1, k_ = q_ & 15;
    float* dst = p.out2 + ((size_t)b * 256 + q_) * 16 + 8 * g2_;
    *(float4*)(dst) = *(const float4*)(F + F_WO + k_ * 16 + 8 * g2_);
    *(float4*)(dst + 4) = *(const float4*)(F + F_WO + k_ * 16 + 8 * g2_ + 4);
  }
  __syncthreads();

  // ---- P10: fv1H staging + AO (8 waves) + AP (w0) + src (w1) ----
#pragma unroll
  for (int qq = 0; qq < 4; qq++) {
    const int e0 = tid * 16 + qq * 4;
    h2* d = (h2*)&SMB[FV1H + (e0 >> 7) * 136 + (e0 & 127)];
    d[0] = h2{(f16)rfv[qq].x, (f16)rfv[qq].y};
    d[1] = h2{(f16)rfv[qq].z, (f16)rfv[qq].w};
  }
  const float* BF = (const float*)(SMB + BACKB);
  const int i_ = ihalf * 8 + w;
  f16* Sl = SMB + SLICE + w * 1536;
  {
    v8h az = {};
    if (quad == 0) {
      const float wv = F[F_WSIG + i_ * 16 + m];
#pragma unroll
      for (int c = 0; c < 8; c++)
        az[c] = (f16)(F[F_PI + m * 8 + c] + wv * (F[F_ACT + m * 8 + c] - F[F_PI + m * 8 + c]));
    }
    v4f acc2[4];
    av_mlp2(SMB + OBSH, SMB + AV1H, SMB + AV2H, BF, BF + 64, Sl, az, lane, acc2);
#pragma unroll
    for (int nt = 0; nt < 4; nt++)
#pragma unroll
      for (int reg = 0; reg < 4; reg++)
        Sl[(nt * 16 + m) * 24 + quad * 4 + reg] = (f16)acc2[nt][reg];
  }
  if (w == 0) {
    v8h az = {};
    if (quad == 0) {
#pragma unroll
      for (int c = 0; c < 8; c++) az[c] = (f16)F[F_PI + m * 8 + c];
    }
    v4f acc2[4];
    av_mlp2(SMB + OBSH, SMB + AV1H, SMB + AV2H, BF, BF + 64, SMB + APTO, az, lane, acc2);
#pragma unroll
    for (int nt = 0; nt < 4; nt++)
#pragma unroll
      for (int reg = 0; reg < 4; reg++)
        SMB[APTO + (nt * 16 + m) * 24 + quad * 4 + reg] = (f16)acc2[nt][reg];
  }
  if (w == 1) {
    v8h az = {};
    if (quad == 0) {
      const float wv = F[F_WSIG + m * 16 + m];
#pragma unroll
      for (int c = 0; c < 8; c++)
        az[c] = (f16)(F[F_PI + m * 8 + c] + wv * (F[F_ACT + m * 8 + c] - F[F_PI + m * 8 + c]));
    }
    v4f acc2[4];
    av_mlp2(SMB + OBSH, SMB + AV1H, SMB + AV2H, BF, BF + 64, SMB + AOSRC, az, lane, acc2);
#pragma unroll
    for (int nt = 0; nt < 4; nt++)
#pragma unroll
      for (int reg = 0; reg < 4; reg++)
        SMB[AOSRC + (quad * 4 + reg) * 72 + nt * 16 + m] = (f16)acc2[nt][reg];
  }
  __syncthreads();

  // ---- P11: mixed + fv1 + fv2 + out0 (all 8 waves) ----
  {
    const v8h am = *(const v8h*)(&SMB[AEXT + m * 40 + quad * 8]);
    v4f macc[4];
#pragma unroll
    for (int nt = 0; nt < 4; nt++) {
      const int oo = nt * 16 + m;
      v8h bf;
      if (quad < 2) {
        bf = *(const v8h*)(Sl + oo * 24 + quad * 8);
      } else {
        const v8h apv = *(const v8h*)(&SMB[APTO + oo * 24 + (quad - 2) * 8]);
        const v8h aov = *(const v8h*)(Sl + oo * 24 + (quad - 2) * 8);
        bf = apv - aov;
      }
      v4f z4 = {0.f, 0.f, 0.f, 0.f};
      macc[nt] = __builtin_amdgcn_mfma_f32_16x16x32_f16(am, bf, z4, 0, 0, 0);
    }
#pragma unroll
    for (int nt = 0; nt < 4; nt++)
#pragma unroll
      for (int reg = 0; reg < 4; reg++)
        Sl[(quad * 4 + reg) * 72 + nt * 16 + m] = (f16)macc[nt][reg];
  }
  {
    const v8h f0 = *(const v8h*)(&SMB[AOSRC + m * 72 + quad * 8]);
    const v8h f1 = *(const v8h*)(&SMB[AOSRC + m * 72 + 32 + quad * 8]);
    const v8h f2 = *(const v8h*)(Sl + m * 72 + quad * 8);
    const v8h f3 = *(const v8h*)(Sl + m * 72 + 32 + quad * 8);
#pragma unroll
    for (int nt = 0; nt < 4; nt++) {
      const float bv = BF[128 + nt * 16 + m];
      v4f acc = {bv, bv, bv, bv};
      acc = __builtin_amdgcn_mfma_f32_16x16x32_f16(f0, bfrag(SMB + FV1H, 136, nt, 0, lane), acc, 0, 0, 0);
      acc = __builtin_amdgcn_mfma_f32_16x16x32_f16(f1, bfrag(SMB + FV1H, 136, nt, 1, lane), acc, 0, 0, 0);
      acc = __builtin_amdgcn_mfma_f32_16x16x32_f16(f2, bfrag(SMB + FV1H, 136, nt, 2, lane), acc, 0, 0, 0);
      acc = __builtin_amdgcn_mfma_f32_16x16x32_f16(f3, bfrag(SMB + FV1H, 136, nt, 3, lane), acc, 0, 0, 0);
#pragma unroll
      for (int reg = 0; reg < 4; reg++)
        Sl[(quad * 4 + reg) * 72 + nt * 16 + m] = (f16)lrelu(acc[reg]);
    }
  }
  {
    const int g2 = quad;
    float y0 = BF[192 + 2 * g2], y1 = BF[192 + 2 * g2 + 1];
#pragma unroll
    for (int o2 = 0; o2 < 32; o2++) {
      const h2 hh = *(const h2*)(Sl + m * 72 + 2 * o2);
      const h2 w0 = *(const h2*)(&SMB[FV2PW + (2 * g2) * 64 + 2 * o2]);
      const h2 w1 = *(const h2*)(&SMB[FV2PW + (2 * g2 + 1) * 64 + 2 * o2]);
      y0 = fdot2f(w0, hh, y0);
      y1 = fdot2f(w1, hh, y1);
    }
    *(float2*)(p.out0 + ((size_t)b * 256 + i_ * 16 + m) * 8 + 2 * g2) = make_float2(y0, y1);
  }
}

extern "C" void kernel_launch(void* const* d_in, const int* in_sizes, int n_in,
                              void* d_out, int out_size, void* d_ws, size_t ws_size,
                              hipStream_t stream) {
  P p;
  p.obs = (const float*)d_in[0];
  p.pol = (const float*)d_in[1];
  p.act = (const float*)d_in[2];
  p.kw1w = (const float*)d_in[3];  p.kw1b = (const float*)d_in[4];
  p.kw2w = (const float*)d_in[5];  p.kw2b = (const float*)d_in[6];
  p.qw1w = (const float*)d_in[7];  p.qw1b = (const float*)d_in[8];
  p.qw2w = (const float*)d_in[9];  p.qw2b = (const float*)d_in[10];
  p.ko1w = (const float*)d_in[11]; p.ko1b = (const float*)d_in[12];
  p.ko2w = (const float*)d_in[13]; p.ko2b = (const float*)d_in[14];
  p.qo1w = (const float*)d_in[15]; p.qo1b = (const float*)d_in[16];
  p.qo2w = (const float*)d_in[17]; p.qo2b = (const float*)d_in[18];
  p.av1w = (const float*)d_in[19]; p.av1b = (const float*)d_in[20];
  p.av2w = (const float*)d_in[21]; p.av2b = (const float*)d_in[22];
  p.fv1w = (const float*)d_in[23]; p.fv1b = (const float*)d_in[24];
  p.fv2w = (const float*)d_in[25]; p.fv2b = (const float*)d_in[26];

  const int Bn = in_sizes[0] / (A_ * DOBS_);   // 128
  p.out0 = (float*)d_out;
  p.out1 = p.out0 + (size_t)Bn * A_ * A_ * NA_;
  p.out2 = p.out1 + (size_t)Bn * A_ * A_;

  const size_t lds_bytes = (size_t)LDS_F16 * sizeof(f16);   // 140864
  (void)hipFuncSetAttribute(reinterpret_cast<const void*>(critic_fused),
                            hipFuncAttributeMaxDynamicSharedMemorySize, (int)lds_bytes);
  hipLaunchKernelGGL(critic_fused, dim3(2 * Bn), dim3(512), lds_bytes, stream, p);
}